// Round 2
// baseline (68.412 us; speedup 1.0000x reference)
//
#include <hip/hip_runtime.h>

// out[k][j] = max( x1[k][j], max_i( W[i][j]*x0[k][i] + B[i][j] + C_norm[i][j] ) )
// N=4096, D=256, all float32.
//
// Scheme: thread owns one j-column (n=1) and m=16 k-rows; 4-way i-split within
// a 1024-thread block. x0 operands are wave-uniform -> scalar loads (SGPR
// operand in v_fma). W/A are per-lane coalesced dwords, each element read once
// per block. No LDS / no barriers in the main loop.

constexpr int Dk = 256;   // D
constexpr int BK = 16;    // k-rows per block
constexpr int QI = 64;    // i's per quarter (4 quarters cover 256)
constexpr int MST = 20;   // merge-scratch stride (floats), 16B-aligned, bank-spread

__global__ void prep_A(const float* __restrict__ B, const float* __restrict__ C,
                       float* __restrict__ A) {
    const int idx = blockIdx.x * blockDim.x + threadIdx.x;   // float4 index, exact
    const float4 b = reinterpret_cast<const float4*>(B)[idx];
    const float4 c = reinterpret_cast<const float4*>(C)[idx];
    float4 a;
    a.x = b.x + c.x; a.y = b.y + c.y; a.z = b.z + c.z; a.w = b.w + c.w;
    reinterpret_cast<float4*>(A)[idx] = a;
}

#define LOADX(wd, ad, i0_) do {                                         \
    _Pragma("unroll")                                                   \
    for (int u = 0; u < 4; ++u) {                                       \
        const int g = ((i0_) + u) * Dk + t;                             \
        wd[u] = W[g];                                                   \
        if (PRE) ad[u] = Ap[g];                                         \
        else     ad[u] = Bm[g] + Cn[g];                                 \
    }                                                                   \
} while (0)

#define COMPUTE(wd, ad, i0_) do {                                       \
    _Pragma("unroll")                                                   \
    for (int k = 0; k < BK; ++k) {                                      \
        const float* xr = x0q + k * Dk + (i0_);                         \
        const float t0 = fmaf(wd[0], xr[0], ad[0]);                     \
        const float t1 = fmaf(wd[1], xr[1], ad[1]);                     \
        const float t2 = fmaf(wd[2], xr[2], ad[2]);                     \
        const float t3 = fmaf(wd[3], xr[3], ad[3]);                     \
        acc[k] = fmaxf(fmaxf(fmaxf(fmaxf(t0, t1), t2), t3), acc[k]);    \
    }                                                                   \
} while (0)

template<bool PRE>
__global__ __launch_bounds__(1024, 1)
void maxplus(const float* __restrict__ x0,
             const float* __restrict__ x1,
             const float* __restrict__ Cn,
             const float* __restrict__ W,
             const float* __restrict__ Bm,
             const float* __restrict__ Ap,
             float* __restrict__ out) {
    __shared__ float mrg[3 * 256 * MST];   // 60 KiB quarter-merge scratch

    const int tid = threadIdx.x;
    const int q = tid >> 8;          // i-quarter 0..3
    const int t = tid & 255;         // output column j = t
    const int k0 = blockIdx.x * BK;

    const float* x0q = x0 + (size_t)k0 * Dk;   // this block's x0 rows (uniform base)

    float acc[BK];
#pragma unroll
    for (int k = 0; k < BK; ++k) acc[k] = -3.402823466e38f;

    const int ibeg = q * QI;

    float wA[4], aA[4], wB[4], aB[4];

    LOADX(wA, aA, ibeg);
    for (int ib = 0; ib < QI / 4; ib += 2) {       // 8 iterations, 2x4 i's each
        const int i0 = ibeg + ib * 4;
        LOADX(wB, aB, i0 + 4);                     // prefetch next 4 i's
        COMPUTE(wA, aA, i0);
        if (ib + 2 < QI / 4) LOADX(wA, aA, i0 + 8);
        COMPUTE(wB, aB, i0 + 4);
    }

    // ---- merge the 4 i-quarters via LDS, quarter 0 finalizes ----
    __syncthreads();
    if (q > 0) {
        float* s = &mrg[((q - 1) * 256 + t) * MST];
#pragma unroll
        for (int c = 0; c < BK; c += 4) {
            *reinterpret_cast<float4*>(&s[c]) =
                make_float4(acc[c], acc[c + 1], acc[c + 2], acc[c + 3]);
        }
    }
    __syncthreads();
    if (q == 0) {
#pragma unroll
        for (int qq = 0; qq < 3; ++qq) {
            const float* s = &mrg[(qq * 256 + t) * MST];
#pragma unroll
            for (int c = 0; c < BK; c += 4) {
                const float4 v = *reinterpret_cast<const float4*>(&s[c]);
                acc[c]     = fmaxf(acc[c],     v.x);
                acc[c + 1] = fmaxf(acc[c + 1], v.y);
                acc[c + 2] = fmaxf(acc[c + 2], v.z);
                acc[c + 3] = fmaxf(acc[c + 3], v.w);
            }
        }
#pragma unroll
        for (int k = 0; k < BK; ++k) {
            const int g = (k0 + k) * Dk + t;
            out[g] = fmaxf(acc[k], x1[g]);   // coalesced dword load+store
        }
    }
}

extern "C" void kernel_launch(void* const* d_in, const int* in_sizes, int n_in,
                              void* d_out, int out_size, void* d_ws, size_t ws_size,
                              hipStream_t stream) {
    const float* x0 = (const float*)d_in[0];
    const float* x1 = (const float*)d_in[1];
    const float* Cn = (const float*)d_in[2];
    const float* W  = (const float*)d_in[3];
    const float* Bm = (const float*)d_in[4];
    float* out = (float*)d_out;

    const int n = in_sizes[0] / Dk;            // 4096
    const int grid = n / BK;                   // 256 blocks of 1024 threads

    const bool pre = ws_size >= (size_t)Dk * Dk * sizeof(float);
    float* Ap = (float*)d_ws;

    if (pre) {
        hipLaunchKernelGGL(prep_A, dim3(Dk * Dk / 4 / 256), dim3(256), 0, stream,
                           Bm, Cn, Ap);
        hipLaunchKernelGGL((maxplus<true>), dim3(grid), dim3(1024), 0, stream,
                           x0, x1, Cn, W, Bm, Ap, out);
    } else {
        hipLaunchKernelGGL((maxplus<false>), dim3(grid), dim3(1024), 0, stream,
                           x0, x1, Cn, W, Bm, Ap, out);
    }
}

// Round 3
// 19.236 us; speedup vs baseline: 3.5565x; 3.5565x over previous
//
#include <hip/hip_runtime.h>

// out[k][j] = max( x1[k][j], max_i( W[i][j]*x0[k][i] + B[i][j] + C_norm[i][j] ) )
// N=4096, D=256, f32 in/out. Math in packed f16 (v_pk_fma_f16 / v_pk_max_f16);
// abs error <= ~0.02 << 0.101 threshold.
//
// 256 blocks x 512 threads. Block tile 64k x 64j. Each of 8 waves computes the
// FULL 64x64 out-tile over a 32-i slice (8 i's per chunk); 4 chunks of 64 i
// double-buffered through 48KB LDS. Per-thread tile 8k x 8j as h2 acc[8][4].
// LDS-tree merge across waves, distributed epilogue (fold x1, f32 store).

typedef _Float16 h16;
typedef h16 h2  __attribute__((ext_vector_type(2)));
typedef h16 h8v __attribute__((ext_vector_type(8)));
typedef float f32x4 __attribute__((ext_vector_type(4)));

constexpr int Dk = 256;

struct __align__(16) Chunk {      // 24 KiB: one 64-i chunk
  h16 W[64 * 64];                 // [i_local][j_local]
  h16 A[64 * 64];                 // B + C_norm
  h16 X0[64 * 64];                // [k_local][i_local], XOR-swizzled
};

__global__ __launch_bounds__(512, 2)
void mp_kernel(const float* __restrict__ x0, const float* __restrict__ x1,
               const float* __restrict__ Cn, const float* __restrict__ Wg,
               const float* __restrict__ Bg, float* __restrict__ out) {
  __shared__ Chunk buf[2];

  const int tid = threadIdx.x;
  const int w   = tid >> 6;        // wave 0..7  (i-slice owner / merge role)
  const int l   = tid & 63;
  const int tk  = l >> 3;          // k-group 0..7  (8 k's each)
  const int tj  = l & 7;           // j-group 0..7  (8 j's each)
  const int kb  = blockIdx.x >> 2;
  const int jb  = blockIdx.x & 3;
  const int k0  = kb * 64;
  const int j0  = jb * 64;

  // staging mapping: 512 threads cover 64 rows x 64 cols (8 elems each)
  const int srow = tid >> 3;           // 0..63
  const int scol = (tid & 7) * 8;      // 0..56
  const int xsw  = scol ^ ((srow >> 3) << 3);   // swizzled x0 col

  h2 acc[8][4];
#pragma unroll
  for (int kk = 0; kk < 8; ++kk)
#pragma unroll
    for (int jp = 0; jp < 4; ++jp)
      acc[kk][jp] = h2{(h16)(-60000.0f), (h16)(-60000.0f)};

  auto stage = [&](int c, Chunk* b) {
    const int i0 = 64 * c;
    const f32x4* wg = reinterpret_cast<const f32x4*>(&Wg[(i0 + srow) * Dk + j0 + scol]);
    const f32x4* bg = reinterpret_cast<const f32x4*>(&Bg[(i0 + srow) * Dk + j0 + scol]);
    const f32x4* cg = reinterpret_cast<const f32x4*>(&Cn[(i0 + srow) * Dk + j0 + scol]);
    const f32x4* xg = reinterpret_cast<const f32x4*>(&x0[(k0 + srow) * Dk + i0 + scol]);
    const f32x4 wv0 = wg[0], wv1 = wg[1];
    const f32x4 av0 = bg[0] + cg[0], av1 = bg[1] + cg[1];
    const f32x4 xv0 = xg[0], xv1 = xg[1];
    h8v hw, ha, hx;
#pragma unroll
    for (int u = 0; u < 4; ++u) {
      hw[u] = (h16)wv0[u];  hw[u + 4] = (h16)wv1[u];
      ha[u] = (h16)av0[u];  ha[u + 4] = (h16)av1[u];
      hx[u] = (h16)xv0[u];  hx[u + 4] = (h16)xv1[u];
    }
    *reinterpret_cast<h8v*>(&b->W [srow * 64 + scol]) = hw;
    *reinterpret_cast<h8v*>(&b->A [srow * 64 + scol]) = ha;
    *reinterpret_cast<h8v*>(&b->X0[srow * 64 + xsw])  = hx;
  };

  auto compute = [&](Chunk* b) {
    const int iloc = 8 * w;                       // this wave's 8-i slice
    h8v xr[8];
#pragma unroll
    for (int kk = 0; kk < 8; ++kk)
      xr[kk] = *reinterpret_cast<const h8v*>(
          &b->X0[(tk * 8 + kk) * 64 + (iloc ^ (tk << 3))]);
#pragma unroll
    for (int ii = 0; ii < 8; ++ii) {
      const h8v wv = *reinterpret_cast<const h8v*>(&b->W[(iloc + ii) * 64 + tj * 8]);
      const h8v av = *reinterpret_cast<const h8v*>(&b->A[(iloc + ii) * 64 + tj * 8]);
      const h2 wp0 = __builtin_shufflevector(wv, wv, 0, 1);
      const h2 wp1 = __builtin_shufflevector(wv, wv, 2, 3);
      const h2 wp2 = __builtin_shufflevector(wv, wv, 4, 5);
      const h2 wp3 = __builtin_shufflevector(wv, wv, 6, 7);
      const h2 ap0 = __builtin_shufflevector(av, av, 0, 1);
      const h2 ap1 = __builtin_shufflevector(av, av, 2, 3);
      const h2 ap2 = __builtin_shufflevector(av, av, 4, 5);
      const h2 ap3 = __builtin_shufflevector(av, av, 6, 7);
#pragma unroll
      for (int kk = 0; kk < 8; ++kk) {
        const h16 e = xr[kk][ii];
        const h2 xb = h2{e, e};
        acc[kk][0] = __builtin_elementwise_max(acc[kk][0], __builtin_elementwise_fma(wp0, xb, ap0));
        acc[kk][1] = __builtin_elementwise_max(acc[kk][1], __builtin_elementwise_fma(wp1, xb, ap1));
        acc[kk][2] = __builtin_elementwise_max(acc[kk][2], __builtin_elementwise_fma(wp2, xb, ap2));
        acc[kk][3] = __builtin_elementwise_max(acc[kk][3], __builtin_elementwise_fma(wp3, xb, ap3));
      }
    }
  };

  // ---- main pipeline: stage(c+1) overlapped with compute(c) ----
  stage(0, &buf[0]);
  __syncthreads();
#pragma unroll
  for (int c = 0; c < 4; ++c) {
    if (c < 3) stage(c + 1, &buf[(c + 1) & 1]);
    compute(&buf[c & 1]);
    __syncthreads();
  }

  // ---- tree merge across waves via LDS (reuses buf, max 32KB) ----
  uint4* mrg = reinterpret_cast<uint4*>(&buf[0]);

  auto wslot = [&](int s) {
#pragma unroll
    for (int kk = 0; kk < 8; ++kk) {
      uint4 u;
      u.x = __builtin_bit_cast(unsigned int, acc[kk][0]);
      u.y = __builtin_bit_cast(unsigned int, acc[kk][1]);
      u.z = __builtin_bit_cast(unsigned int, acc[kk][2]);
      u.w = __builtin_bit_cast(unsigned int, acc[kk][3]);
      mrg[(s * 8 + kk) * 64 + l] = u;
    }
  };
  auto rmerge = [&](int s) {
#pragma unroll
    for (int kk = 0; kk < 8; ++kk) {
      const uint4 u = mrg[(s * 8 + kk) * 64 + l];
      acc[kk][0] = __builtin_elementwise_max(acc[kk][0], __builtin_bit_cast(h2, u.x));
      acc[kk][1] = __builtin_elementwise_max(acc[kk][1], __builtin_bit_cast(h2, u.y));
      acc[kk][2] = __builtin_elementwise_max(acc[kk][2], __builtin_bit_cast(h2, u.z));
      acc[kk][3] = __builtin_elementwise_max(acc[kk][3], __builtin_bit_cast(h2, u.w));
    }
  };

  if (w >= 4) wslot(w - 4);
  __syncthreads();
  if (w < 4) rmerge(w);
  __syncthreads();
  if (w == 2 || w == 3) wslot(w - 2);
  __syncthreads();
  if (w < 2) rmerge(w);
  __syncthreads();
  if (w == 1) wslot(0);
  __syncthreads();
  if (w == 0) { rmerge(0); wslot(0); }   // final result lands in slot 0: [kk*64 + l]
  __syncthreads();

  // ---- distributed epilogue: thread t handles (kk = w, lane l) ----
  {
    const uint4 u = mrg[w * 64 + l];          // = mrg[tid], contiguous
    const h2 p0 = __builtin_bit_cast(h2, u.x);
    const h2 p1 = __builtin_bit_cast(h2, u.y);
    const h2 p2 = __builtin_bit_cast(h2, u.z);
    const h2 p3 = __builtin_bit_cast(h2, u.w);
    const int k = k0 + (l >> 3) * 8 + w;
    const int j = j0 + (l & 7) * 8;
    f32x4 o0 = { (float)p0[0], (float)p0[1], (float)p1[0], (float)p1[1] };
    f32x4 o1 = { (float)p2[0], (float)p2[1], (float)p3[0], (float)p3[1] };
    const f32x4* xg = reinterpret_cast<const f32x4*>(&x1[k * Dk + j]);
    o0 = __builtin_elementwise_max(o0, xg[0]);
    o1 = __builtin_elementwise_max(o1, xg[1]);
    f32x4* og = reinterpret_cast<f32x4*>(&out[k * Dk + j]);
    og[0] = o0;
    og[1] = o1;
  }
}

extern "C" void kernel_launch(void* const* d_in, const int* in_sizes, int n_in,
                              void* d_out, int out_size, void* d_ws, size_t ws_size,
                              hipStream_t stream) {
  const float* x0 = (const float*)d_in[0];
  const float* x1 = (const float*)d_in[1];
  const float* Cn = (const float*)d_in[2];
  const float* W  = (const float*)d_in[3];
  const float* Bm = (const float*)d_in[4];
  float* out = (float*)d_out;

  const int n = in_sizes[0] / Dk;          // 4096
  const int grid = (n / 64) * 4;           // 64 k-blocks x 4 j-blocks = 256
  hipLaunchKernelGGL(mp_kernel, dim3(grid), dim3(512), 0, stream,
                     x0, x1, Cn, W, Bm, out);
}